// Round 8
// baseline (948.851 us; speedup 1.0000x reference)
//
#include <hip/hip_runtime.h>
#include <hip/hip_bf16.h>

#define H  4096
#define V  4
#define OUT_N 4
#define MS 104
#define MD 3
#define R3H (3 * H)     // 12288 rows of w_hh

__device__ __forceinline__ float b2f(unsigned short u) {
    return __uint_as_float(((unsigned int)u) << 16);
}
__device__ __forceinline__ float ldf(const void* p, size_t i, bool is_f32) {
    return is_f32 ? ((const float*)p)[i] : b2f(((const unsigned short*)p)[i]);
}
__device__ __forceinline__ void stf(void* p, size_t i, bool is_f32, float v) {
    if (is_f32) ((float*)p)[i] = v;
    else        ((__hip_bfloat16*)p)[i] = __float2bfloat16(v);
}

// Wave-uniform dtype detection: decode first 1024 ushorts of w_hh as bf16.
// Real bf16 weights are all |x| <~ 0.2; f32 storage yields random-exponent
// halves (42%/elem chance of |x|>1e6). 2 KB, L2-hot after first wave.
__device__ __forceinline__ bool detect_f32(const void* w_hh) {
    const unsigned short* w = (const unsigned short*)w_hh;
    const int lane = threadIdx.x & 63;
    int bad = 0;
    #pragma unroll
    for (int i = 0; i < 16; ++i) {
        const float v = b2f(w[lane + (i << 6)]);
        if (!(fabsf(v) < 1.0e6f)) bad = 1;
    }
    return __ballot(bad) != 0ull;
}

// 8 bf16 (as uint4) dotted against 8 f32 (two float4).
__device__ __forceinline__ float dot8(uint4 a, float4 h0, float4 h1) {
    return __uint_as_float(a.x << 16)          * h0.x
         + __uint_as_float(a.x & 0xffff0000u)  * h0.y
         + __uint_as_float(a.y << 16)          * h0.z
         + __uint_as_float(a.y & 0xffff0000u)  * h0.w
         + __uint_as_float(a.z << 16)          * h1.x
         + __uint_as_float(a.z & 0xffff0000u)  * h1.y
         + __uint_as_float(a.w << 16)          * h1.z
         + __uint_as_float(a.w & 0xffff0000u)  * h1.w;
}
__device__ __forceinline__ float dot4(float4 a, float4 b) {
    return a.x * b.x + a.y * b.y + a.z * b.z + a.w * b.w;
}
__device__ __forceinline__ float wave_reduce(float a) {
    #pragma unroll
    for (int off = 32; off > 0; off >>= 1) a += __shfl_down(a, off);
    return a;
}

// ---------------------------------------------------------------------------
// h_bar[j] = w_sh[j,:] . stack[0,:] + b_sh[j] + hidden0[j]  (fp32 into ws).
// Also zeroes the per-k arrival counter. 16 blocks x 256.
// ---------------------------------------------------------------------------
__global__ __launch_bounds__(256) void hbar_kernel(
    const void* __restrict__ w_sh, const void* __restrict__ b_sh,
    const void* __restrict__ hidden0, const void* __restrict__ stack,
    const void* __restrict__ w_hh, float* __restrict__ h_bar,
    int* __restrict__ cnt) {
    const bool f32 = detect_f32(w_hh);
    const float s0 = ldf(stack, 0, f32);
    const float s1 = ldf(stack, 1, f32);
    const float s2 = ldf(stack, 2, f32);
    const int j = blockIdx.x * 256 + threadIdx.x;   // grid is exactly H/256
    cnt[j] = 0;
    h_bar[j] = ldf(w_sh, (size_t)j * 3 + 0, f32) * s0
             + ldf(w_sh, (size_t)j * 3 + 1, f32) * s1
             + ldf(w_sh, (size_t)j * 3 + 2, f32) * s2
             + ldf(b_sh, j, f32) + ldf(hidden0, j, f32);
}

// ---------------------------------------------------------------------------
// One WAVE per w_hh ROW (12288 waves = 32 waves/CU, the TLP maximum).
// - h_bar staged once per block into LDS (16 KB) -> vmcnt queue holds ONLY
//   the row stream: 8 (bf16) / 16 (f32) fully-independent 16 B loads/lane
//   covering the whole 8/16 KB row in one shot.
// - Full-row dot -> wave_reduce -> gh[r] (one writer per row, plain store).
// - GRU gate finish fused via per-k arrival counter: the 3rd-arriving row
//   wave (threadfence + device atomicAdd, pattern validated in R3's passing
//   run) reads the other two partials and finishes gate k inline.
// 3072 blocks x 256 thr (4 waves), ~64 VGPR, LDS 16 KB.
// ---------------------------------------------------------------------------
__global__ __launch_bounds__(256) void rows_kernel(
    const int*  __restrict__ inp,  const void* __restrict__ emb,
    const void* __restrict__ w_ih, const void* __restrict__ w_hh,
    const void* __restrict__ b_ih, const void* __restrict__ b_hh,
    const float* __restrict__ h_bar,
    float* __restrict__ gh, int* __restrict__ cnt,
    float* __restrict__ h_f32, void* __restrict__ out) {
    const bool f32 = detect_f32(w_hh);
    const int t = threadIdx.x, wave = t >> 6, lane = t & 63;
    const int r = blockIdx.x * 4 + wave;     // row 0..12287
    const int k = r & (H - 1);               // hidden index

    __shared__ float4 hb4[H / 4];            // 16 KB h_bar copy
    {
        const float4* src = (const float4*)h_bar;
        #pragma unroll
        for (int i = 0; i < 4; ++i) hb4[t + 256 * i] = src[t + 256 * i];
    }
    __syncthreads();

    // ---- full-row dot ------------------------------------------------------
    float acc = 0.f;
    if (f32) {
        const float4* W = (const float4*)w_hh + (size_t)r * (H / 4);
        float4 a[16];
        #pragma unroll
        for (int i = 0; i < 16; ++i) a[i] = W[i * 64 + lane];
        #pragma unroll
        for (int i = 0; i < 16; ++i) acc += dot4(a[i], hb4[i * 64 + lane]);
    } else {
        const uint4* W = (const uint4*)w_hh + (size_t)r * (H / 8);
        uint4 a[8];
        #pragma unroll
        for (int i = 0; i < 8; ++i) a[i] = W[i * 64 + lane];
        #pragma unroll
        for (int i = 0; i < 8; ++i)
            acc += dot8(a[i], hb4[i * 128 + lane * 2], hb4[i * 128 + lane * 2 + 1]);
    }
    acc = wave_reduce(acc);

    // ---- publish partial; 3rd arriver finishes gate k ----------------------
    if (lane == 0) {
        gh[r] = acc;
        __threadfence();                               // release gh[r]
        const int old = atomicAdd(&cnt[k], 1);         // device scope
        if (old == 2) {
            __threadfence();                           // acquire others' gh
            const float sr = gh[k];
            const float sz = gh[k + H];
            const float sn = gh[k + 2 * H];

            const int idx = inp[0];
            float x[V];
            #pragma unroll
            for (int c = 0; c < V; ++c) x[c] = ldf(emb, (size_t)idx * V + c, f32);

            float gi[3];
            #pragma unroll
            for (int gg = 0; gg < 3; ++gg) {
                float a = ldf(b_ih, (size_t)(k + gg * H), f32);
                #pragma unroll
                for (int c = 0; c < V; ++c)
                    a += ldf(w_ih, (size_t)(k + gg * H) * V + c, f32) * x[c];
                gi[gg] = a;
            }
            const float ghr = sr + ldf(b_hh, (size_t)k,           f32);
            const float ghz = sz + ldf(b_hh, (size_t)(k + H),     f32);
            const float ghn = sn + ldf(b_hh, (size_t)(k + 2 * H), f32);

            const float rr = 1.f / (1.f + expf(-(gi[0] + ghr)));
            const float zz = 1.f / (1.f + expf(-(gi[1] + ghz)));
            const float nn = tanhf(gi[2] + rr * ghn);
            const float hk = (1.f - zz) * nn + zz * h_bar[k];

            h_f32[k] = hk;
            stf(out, (size_t)(OUT_N + k), f32, hk);    // hidden output
        }
    }
}

// ---------------------------------------------------------------------------
// Heads: one row-dot per WAVE (9 of 16 waves active), single barrier, then
// sigmoid/softmax + differentiable stack blend. ~72-144 KB cold reads.
// ---------------------------------------------------------------------------
__global__ __launch_bounds__(1024) void heads_kernel(
    const float* __restrict__ h,
    const void* __restrict__ w_y, const void* __restrict__ b_y,
    const void* __restrict__ w_a, const void* __restrict__ b_a,
    const void* __restrict__ w_n, const void* __restrict__ b_n,
    const void* __restrict__ stack, const void* __restrict__ w_hh,
    void* __restrict__ out) {
    const bool f32 = detect_f32(w_hh);
    const int t = threadIdx.x, wave = t >> 6, lane = t & 63;

    __shared__ float scal[9];
    if (wave < 9) {
        const void* base; size_t row;
        if (wave < 4)      { base = w_y; row = (size_t)wave * H; }
        else if (wave < 6) { base = w_a; row = (size_t)(wave - 4) * H; }
        else               { base = w_n; row = (size_t)(wave - 6) * H; }

        float acc = 0.f;
        if (f32) {
            const float4* W  = (const float4*)((const float*)base + row);
            const float4* Hv = (const float4*)h;
            #pragma unroll 4
            for (int it = 0; it < H / 256; ++it) {
                const int i = (it << 6) + lane;
                acc += dot4(W[i], Hv[i]);
            }
        } else {
            const uint4*  W  = (const uint4*)((const unsigned short*)base + row);
            const float4* Hv = (const float4*)h;
            #pragma unroll 2
            for (int it = 0; it < H / 512; ++it) {
                const int i = (it << 6) + lane;
                acc += dot8(W[i], Hv[2 * i], Hv[2 * i + 1]);
            }
        }
        acc = wave_reduce(acc);
        if (lane == 0) scal[wave] = acc;
    }
    __syncthreads();

    __shared__ float act0, act1, ne[MD];
    if (t == 0) {
        const float a0 = scal[4] + ldf(b_a, 0, f32);
        const float a1 = scal[5] + ldf(b_a, 1, f32);
        const float m  = fmaxf(a0, a1);
        const float e0 = expf(a0 - m), e1 = expf(a1 - m);
        const float inv = 1.f / (e0 + e1);
        act0 = e0 * inv; act1 = e1 * inv;
    }
    if (t < OUT_N)
        stf(out, (size_t)t, f32,
            1.f / (1.f + expf(-(scal[t] + ldf(b_y, t, f32)))));
    if (t < MD)
        ne[t] = 1.f / (1.f + expf(-(scal[6 + t] + ldf(b_n, t, f32))));
    __syncthreads();

    const float a0 = act0, a1 = act1;
    for (int idx = t; idx < MS * MD; idx += 1024) {
        const int i = idx / MD;
        const int d = idx - i * MD;
        const float push = (i == 0)      ? ne[d] : ldf(stack, (size_t)(idx - MD), f32);
        const float pop  = (i == MS - 1) ? 0.f   : ldf(stack, (size_t)(idx + MD), f32);
        stf(out, (size_t)(OUT_N + H + idx), f32, a0 * push + a1 * pop);
    }
}

extern "C" void kernel_launch(void* const* d_in, const int* in_sizes, int n_in,
                              void* d_out, int out_size, void* d_ws, size_t ws_size,
                              hipStream_t stream) {
    const int* inp      = (const int*)d_in[0];
    const void* hidden0 = d_in[1];
    const void* stack   = d_in[2];
    const void* emb     = d_in[3];
    const void* w_ih    = d_in[4];
    const void* w_hh    = d_in[5];
    const void* b_ih    = d_in[6];
    const void* b_hh    = d_in[7];
    const void* w_y     = d_in[8];
    const void* b_y     = d_in[9];
    const void* w_n     = d_in[10];
    const void* b_n     = d_in[11];
    const void* w_a     = d_in[12];
    const void* b_a     = d_in[13];
    const void* w_sh    = d_in[14];
    const void* b_sh    = d_in[15];

    float* gh    = (float*)d_ws;          // 3H fp32  = 48 KB  (row partials)
    int*   cnt   = (int*)(gh + R3H);      // H  int   = 16 KB  (arrival count)
    float* h_bar = (float*)(cnt + H);     // H  fp32  = 16 KB
    float* h     = h_bar + H;             // H  fp32  = 16 KB  (96 KB total)

    hbar_kernel<<<H / 256, 256, 0, stream>>>(w_sh, b_sh, hidden0, stack,
                                             w_hh, h_bar, cnt);
    rows_kernel<<<R3H / 4, 256, 0, stream>>>(inp, emb, w_ih, w_hh, b_ih, b_hh,
                                             h_bar, gh, cnt, h, d_out);
    heads_kernel<<<1, 1024, 0, stream>>>(h, w_y, b_y, w_a, b_a, w_n, b_n,
                                         stack, w_hh, d_out);
}

// Round 10
// 310.951 us; speedup vs baseline: 3.0515x; 3.0515x over previous
//
#include <hip/hip_runtime.h>
#include <hip/hip_bf16.h>

#define H  4096
#define V  4
#define OUT_N 4
#define MS 104
#define MD 3

__device__ __forceinline__ float b2f(unsigned short u) {
    return __uint_as_float(((unsigned int)u) << 16);
}
__device__ __forceinline__ float ldf(const void* p, size_t i, bool is_f32) {
    return is_f32 ? ((const float*)p)[i] : b2f(((const unsigned short*)p)[i]);
}
__device__ __forceinline__ void stf(void* p, size_t i, bool is_f32, float v) {
    if (is_f32) ((float*)p)[i] = v;
    else        ((__hip_bfloat16*)p)[i] = __float2bfloat16(v);
}

// Wave-uniform dtype detection: decode first 1024 ushorts of w_hh as bf16.
// Real bf16 weights are all |x| <~ 0.2; f32 storage yields random-exponent
// halves (42%/elem chance of |x|>1e6). 2 KB, L1/L2-hot after first wave.
__device__ __forceinline__ bool detect_f32(const void* w_hh) {
    const unsigned short* w = (const unsigned short*)w_hh;
    const int lane = threadIdx.x & 63;
    int bad = 0;
    #pragma unroll
    for (int i = 0; i < 16; ++i) {
        const float v = b2f(w[lane + (i << 6)]);
        if (!(fabsf(v) < 1.0e6f)) bad = 1;
    }
    return __ballot(bad) != 0ull;
}

// 8 bf16 (as uint4) dotted against 8 f32 (two float4).
__device__ __forceinline__ float dot8(uint4 a, float4 h0, float4 h1) {
    return __uint_as_float(a.x << 16)          * h0.x
         + __uint_as_float(a.x & 0xffff0000u)  * h0.y
         + __uint_as_float(a.y << 16)          * h0.z
         + __uint_as_float(a.y & 0xffff0000u)  * h0.w
         + __uint_as_float(a.z << 16)          * h1.x
         + __uint_as_float(a.z & 0xffff0000u)  * h1.y
         + __uint_as_float(a.w << 16)          * h1.z
         + __uint_as_float(a.w & 0xffff0000u)  * h1.w;
}

__device__ __forceinline__ float dot4(float4 a, float4 b) {
    return a.x * b.x + a.y * b.y + a.z * b.z + a.w * b.w;
}

__device__ __forceinline__ float wave_reduce(float a) {
    #pragma unroll
    for (int off = 32; off > 0; off >>= 1) a += __shfl_down(a, off);
    return a;
}

// ---------------------------------------------------------------------------
// h_bar[j] = w_sh[j,:] . stack[0,:] + b_sh[j] + hidden0[j]  (fp32 into ws).
// 80 KB total traffic, computed once. 16 blocks x 256.
// ---------------------------------------------------------------------------
__global__ __launch_bounds__(256) void hbar_kernel(
    const void* __restrict__ w_sh, const void* __restrict__ b_sh,
    const void* __restrict__ hidden0, const void* __restrict__ stack,
    const void* __restrict__ w_hh, float* __restrict__ h_bar) {
    const bool f32 = detect_f32(w_hh);
    const float s0 = ldf(stack, 0, f32);
    const float s1 = ldf(stack, 1, f32);
    const float s2 = ldf(stack, 2, f32);
    const int j = blockIdx.x * 256 + threadIdx.x;   // grid is exactly H/256
    h_bar[j] = ldf(w_sh, (size_t)j * 3 + 0, f32) * s0
             + ldf(w_sh, (size_t)j * 3 + 1, f32) * s1
             + ldf(w_sh, (size_t)j * 3 + 2, f32) * s2
             + ldf(b_sh, j, f32) + ldf(hidden0, j, f32);
}

// ---------------------------------------------------------------------------
// One WAVE per hidden index k (proven best structure; 314.0 us with R1 tying
// at 314.1 despite different ILP depth -> harness-floor dominated):
//   1. h_bar slice preloaded into VGPRs per lane (L2-hot, one-time) so the
//      streaming vmcnt queue holds ONLY w_hh loads.
//   2. 12 independent w_hh loads (3 rows x 4 iters, explicit variables,
//      constant indices) issued before any FMA -> 192 B/lane in flight.
// 1024 blocks x 256 thr (4 waves). No fences, no atomics (R3/R8: a device
// __threadfence costs ~60 ns serialized; any fence-based fusion regresses).
// ---------------------------------------------------------------------------
__global__ __launch_bounds__(256) void gru_kernel(
    const int*  __restrict__ inp,  const void* __restrict__ emb,
    const void* __restrict__ w_ih, const void* __restrict__ w_hh,
    const void* __restrict__ b_ih, const void* __restrict__ b_hh,
    const float* __restrict__ h_bar, float* __restrict__ h_f32,
    void* __restrict__ out) {
    const bool f32 = detect_f32(w_hh);
    const int wave = threadIdx.x >> 6, lane = threadIdx.x & 63;
    const int k = (blockIdx.x << 2) + wave;

    float ar = 0.f, az = 0.f, an = 0.f;
    if (f32) {
        // h_bar: lane slice = elems {i*256 + lane*4 .. +3}, i = 0..15.
        const float4* HB = (const float4*)h_bar;
        float4 hb[16];
        #pragma unroll
        for (int i = 0; i < 16; ++i) hb[i] = HB[i * 64 + lane];

        const float4* W0 = (const float4*)w_hh + (size_t)k           * (H / 4);
        const float4* W1 = (const float4*)w_hh + (size_t)(k + H)     * (H / 4);
        const float4* W2 = (const float4*)w_hh + (size_t)(k + 2 * H) * (H / 4);
        #pragma unroll
        for (int c = 0; c < 4; ++c) {            // 4 chunks x 4 iters
            float4 a0, a1, a2, a3, b0, b1, b2, b3, d0, d1, d2, d3;
            const int i0 = (c * 4 + 0) * 64 + lane;
            const int i1 = (c * 4 + 1) * 64 + lane;
            const int i2 = (c * 4 + 2) * 64 + lane;
            const int i3 = (c * 4 + 3) * 64 + lane;
            a0 = W0[i0]; a1 = W0[i1]; a2 = W0[i2]; a3 = W0[i3];
            b0 = W1[i0]; b1 = W1[i1]; b2 = W1[i2]; b3 = W1[i3];
            d0 = W2[i0]; d1 = W2[i1]; d2 = W2[i2]; d3 = W2[i3];
            ar += dot4(a0, hb[c*4+0]) + dot4(a1, hb[c*4+1])
                + dot4(a2, hb[c*4+2]) + dot4(a3, hb[c*4+3]);
            az += dot4(b0, hb[c*4+0]) + dot4(b1, hb[c*4+1])
                + dot4(b2, hb[c*4+2]) + dot4(b3, hb[c*4+3]);
            an += dot4(d0, hb[c*4+0]) + dot4(d1, hb[c*4+1])
                + dot4(d2, hb[c*4+2]) + dot4(d3, hb[c*4+3]);
        }
    } else {
        // h_bar: lane slice = elems {i*512 + lane*8 .. +7}, i = 0..7.
        const float4* HB = (const float4*)h_bar;
        float4 hb0[8], hb1[8];
        #pragma unroll
        for (int i = 0; i < 8; ++i) {
            hb0[i] = HB[i * 128 + lane * 2];
            hb1[i] = HB[i * 128 + lane * 2 + 1];
        }

        const uint4* W0 = (const uint4*)w_hh + (size_t)k           * (H / 8);
        const uint4* W1 = (const uint4*)w_hh + (size_t)(k + H)     * (H / 8);
        const uint4* W2 = (const uint4*)w_hh + (size_t)(k + 2 * H) * (H / 8);
        #pragma unroll
        for (int c = 0; c < 2; ++c) {            // 2 chunks x 4 iters
            uint4 a0, a1, a2, a3, b0, b1, b2, b3, d0, d1, d2, d3;
            const int i0 = (c * 4 + 0) * 64 + lane;
            const int i1 = (c * 4 + 1) * 64 + lane;
            const int i2 = (c * 4 + 2) * 64 + lane;
            const int i3 = (c * 4 + 3) * 64 + lane;
            a0 = W0[i0]; a1 = W0[i1]; a2 = W0[i2]; a3 = W0[i3];
            b0 = W1[i0]; b1 = W1[i1]; b2 = W1[i2]; b3 = W1[i3];
            d0 = W2[i0]; d1 = W2[i1]; d2 = W2[i2]; d3 = W2[i3];
            ar += dot8(a0, hb0[c*4+0], hb1[c*4+0]) + dot8(a1, hb0[c*4+1], hb1[c*4+1])
                + dot8(a2, hb0[c*4+2], hb1[c*4+2]) + dot8(a3, hb0[c*4+3], hb1[c*4+3]);
            az += dot8(b0, hb0[c*4+0], hb1[c*4+0]) + dot8(b1, hb0[c*4+1], hb1[c*4+1])
                + dot8(b2, hb0[c*4+2], hb1[c*4+2]) + dot8(b3, hb0[c*4+3], hb1[c*4+3]);
            an += dot8(d0, hb0[c*4+0], hb1[c*4+0]) + dot8(d1, hb0[c*4+1], hb1[c*4+1])
                + dot8(d2, hb0[c*4+2], hb1[c*4+2]) + dot8(d3, hb0[c*4+3], hb1[c*4+3]);
        }
    }

    ar = wave_reduce(ar);
    az = wave_reduce(az);
    an = wave_reduce(an);

    if (lane == 0) {
        const int idx = inp[0];
        float x[V];
        #pragma unroll
        for (int c = 0; c < V; ++c) x[c] = ldf(emb, (size_t)idx * V + c, f32);

        float gi[3];
        #pragma unroll
        for (int g = 0; g < 3; ++g) {
            float a = ldf(b_ih, (size_t)(k + g * H), f32);
            #pragma unroll
            for (int c = 0; c < V; ++c)
                a += ldf(w_ih, (size_t)(k + g * H) * V + c, f32) * x[c];
            gi[g] = a;
        }
        const float ghr = ar + ldf(b_hh, (size_t)k,           f32);
        const float ghz = az + ldf(b_hh, (size_t)(k + H),     f32);
        const float ghn = an + ldf(b_hh, (size_t)(k + 2 * H), f32);

        const float r = 1.f / (1.f + expf(-(gi[0] + ghr)));
        const float z = 1.f / (1.f + expf(-(gi[1] + ghz)));
        const float n = tanhf(gi[2] + r * ghn);
        const float hk = (1.f - z) * n + z * h_bar[k];

        h_f32[k] = hk;
        stf(out, (size_t)(OUT_N + k), f32, hk);   // hidden output
    }
}

// ---------------------------------------------------------------------------
// Heads: one row-dot per WAVE (9 of 16 waves active), single barrier, then
// sigmoid/softmax + differentiable stack blend. ~72-144 KB cold reads.
// ---------------------------------------------------------------------------
__global__ __launch_bounds__(1024) void heads_kernel(
    const float* __restrict__ h,
    const void* __restrict__ w_y, const void* __restrict__ b_y,
    const void* __restrict__ w_a, const void* __restrict__ b_a,
    const void* __restrict__ w_n, const void* __restrict__ b_n,
    const void* __restrict__ stack, const void* __restrict__ w_hh,
    void* __restrict__ out) {
    const bool f32 = detect_f32(w_hh);
    const int t = threadIdx.x, wave = t >> 6, lane = t & 63;

    __shared__ float scal[9];
    if (wave < 9) {
        const void* base; size_t row;
        if (wave < 4)      { base = w_y; row = (size_t)wave * H; }
        else if (wave < 6) { base = w_a; row = (size_t)(wave - 4) * H; }
        else               { base = w_n; row = (size_t)(wave - 6) * H; }

        float acc = 0.f;
        if (f32) {
            const float4* W  = (const float4*)((const float*)base + row);
            const float4* Hv = (const float4*)h;
            #pragma unroll 4
            for (int it = 0; it < H / 256; ++it) {
                const int i = (it << 6) + lane;
                acc += dot4(W[i], Hv[i]);
            }
        } else {
            const uint4*  W  = (const uint4*)((const unsigned short*)base + row);
            const float4* Hv = (const float4*)h;
            #pragma unroll 2
            for (int it = 0; it < H / 512; ++it) {
                const int i = (it << 6) + lane;
                acc += dot8(W[i], Hv[2 * i], Hv[2 * i + 1]);
            }
        }
        acc = wave_reduce(acc);
        if (lane == 0) scal[wave] = acc;
    }
    __syncthreads();

    __shared__ float act0, act1, ne[MD];
    if (t == 0) {
        const float a0 = scal[4] + ldf(b_a, 0, f32);
        const float a1 = scal[5] + ldf(b_a, 1, f32);
        const float m  = fmaxf(a0, a1);
        const float e0 = expf(a0 - m), e1 = expf(a1 - m);
        const float inv = 1.f / (e0 + e1);
        act0 = e0 * inv; act1 = e1 * inv;
    }
    if (t < OUT_N)
        stf(out, (size_t)t, f32,
            1.f / (1.f + expf(-(scal[t] + ldf(b_y, t, f32)))));
    if (t < MD)
        ne[t] = 1.f / (1.f + expf(-(scal[6 + t] + ldf(b_n, t, f32))));
    __syncthreads();

    const float a0 = act0, a1 = act1;
    for (int idx = t; idx < MS * MD; idx += 1024) {
        const int i = idx / MD;
        const int d = idx - i * MD;
        const float push = (i == 0)      ? ne[d] : ldf(stack, (size_t)(idx - MD), f32);
        const float pop  = (i == MS - 1) ? 0.f   : ldf(stack, (size_t)(idx + MD), f32);
        stf(out, (size_t)(OUT_N + H + idx), f32, a0 * push + a1 * pop);
    }
}

extern "C" void kernel_launch(void* const* d_in, const int* in_sizes, int n_in,
                              void* d_out, int out_size, void* d_ws, size_t ws_size,
                              hipStream_t stream) {
    const int* inp      = (const int*)d_in[0];
    const void* hidden0 = d_in[1];
    const void* stack   = d_in[2];
    const void* emb     = d_in[3];
    const void* w_ih    = d_in[4];
    const void* w_hh    = d_in[5];
    const void* b_ih    = d_in[6];
    const void* b_hh    = d_in[7];
    const void* w_y     = d_in[8];
    const void* b_y     = d_in[9];
    const void* w_n     = d_in[10];
    const void* b_n     = d_in[11];
    const void* w_a     = d_in[12];
    const void* b_a     = d_in[13];
    const void* w_sh    = d_in[14];
    const void* b_sh    = d_in[15];

    float* h_bar = (float*)d_ws;          // H fp32
    float* h     = h_bar + H;             // H fp32   (32 KB total workspace)

    hbar_kernel<<<H / 256, 256, 0, stream>>>(w_sh, b_sh, hidden0, stack,
                                             w_hh, h_bar);
    gru_kernel<<<H / 4, 256, 0, stream>>>(inp, emb, w_ih, w_hh, b_ih, b_hh,
                                          h_bar, h, d_out);
    heads_kernel<<<1, 1024, 0, stream>>>(h, w_y, b_y, w_a, b_a, w_n, b_n,
                                         stack, w_hh, d_out);
}